// Round 2
// baseline (192.174 us; speedup 1.0000x reference)
//
#include <hip/hip_runtime.h>
#include <math.h>

typedef __attribute__((ext_vector_type(8))) short short8;
typedef __attribute__((ext_vector_type(4))) float f32x4;

constexpr int D    = 64;
constexpr int TILE = 64;

// split f into bf16 hi + bf16 lo via truncation: f = hi + r exactly, lo = trunc_bf16(r).
// total representation error <= 2^-16 |f|  (plus dropped lo*lo in the product).
__device__ inline void split8(const float* v, short8& hi, short8& lo) {
    #pragma unroll
    for (int j = 0; j < 8; ++j) {
        unsigned u = __builtin_bit_cast(unsigned, v[j]);
        hi[j] = (short)(u >> 16);
        float hf = __builtin_bit_cast(float, u & 0xffff0000u);
        float r  = v[j] - hf;                       // exact
        lo[j] = (short)(__builtin_bit_cast(unsigned, r) >> 16);
    }
}

__global__ __launch_bounds__(256) void cosgauss_kernel(
    const float* __restrict__ x, const float* __restrict__ y,
    const float* __restrict__ mu, const float* __restrict__ ls2,
    float* __restrict__ out, int N, int M)
{
    __shared__ float s2s[D], smu[D];                    // exp(ls2), mu
    __shared__ float sx2[TILE], smx[TILE], sy2[TILE], smy[TILE];

    const int b  = blockIdx.z;
    const int n0 = blockIdx.y * TILE;
    const int m0 = blockIdx.x * TILE;
    const int t  = threadIdx.x;

    if (t < D) { s2s[t] = __expf(ls2[t]); smu[t] = mu[t]; }
    __syncthreads();

    // ---- per-row stats from global (inputs are L2/L3 resident) ----
    if (t < 64) {
        const float* p = x + ((size_t)b * N + n0 + t) * D;
        float a2 = 0.f, am = 0.f;
        #pragma unroll
        for (int d = 0; d < D; d += 4) {
            float4 v = *(const float4*)(p + d);
            float4 s = *(const float4*)&s2s[d];
            float4 m = *(const float4*)&smu[d];
            a2 += v.x*v.x*s.x + v.y*v.y*s.y + v.z*v.z*s.z + v.w*v.w*s.w;
            am += v.x*m.x + v.y*m.y + v.z*m.z + v.w*m.w;
        }
        sx2[t] = a2; smx[t] = am;
    } else if (t < 128) {
        const int r2 = t - 64;
        const float* p = y + ((size_t)b * M + m0 + r2) * D;
        float a2 = 0.f, am = 0.f;
        #pragma unroll
        for (int d = 0; d < D; d += 4) {
            float4 v = *(const float4*)(p + d);
            float4 s = *(const float4*)&s2s[d];
            float4 m = *(const float4*)&smu[d];
            a2 += v.x*v.x*s.x + v.y*v.y*s.y + v.z*v.z*s.z + v.w*v.w*s.w;
            am += v.x*m.x + v.y*m.y + v.z*m.z + v.w*m.w;
        }
        sy2[r2] = a2; smy[r2] = am;
    }
    __syncthreads();

    // ---- MFMA main: 4 waves in 2x2, each wave 32x32 outputs (2x2 tiles of 16x16) ----
    const int w    = t >> 6;
    const int lane = t & 63;
    const int wr   = w >> 1, wc = w & 1;
    const int l15  = lane & 15, lg = lane >> 4;

    f32x4 acc[2][2];
    #pragma unroll
    for (int i = 0; i < 2; ++i)
        #pragma unroll
        for (int j = 0; j < 2; ++j)
            acc[i][j] = (f32x4){0.f, 0.f, 0.f, 0.f};

    const float* xb = x + ((size_t)b * N + n0) * D;
    const float* yb = y + ((size_t)b * M + m0) * D;

    #pragma unroll
    for (int kc = 0; kc < 2; ++kc) {
        const int k0 = kc * 32 + lg * 8;          // this lane's 8-wide k-slice
        float sc[8];
        *(float4*)&sc[0] = *(const float4*)&s2s[k0];
        *(float4*)&sc[4] = *(const float4*)&s2s[k0 + 4];

        short8 ah[2], al[2], bh[2], bl[2];
        #pragma unroll
        for (int i = 0; i < 2; ++i) {
            const float* p = xb + (size_t)(wr * 32 + i * 16 + l15) * D + k0;
            float v[8];
            *(float4*)&v[0] = *(const float4*)p;
            *(float4*)&v[4] = *(const float4*)(p + 4);
            #pragma unroll
            for (int j = 0; j < 8; ++j) v[j] *= sc[j];   // one-sided s2 scaling
            split8(v, ah[i], al[i]);
        }
        #pragma unroll
        for (int jj = 0; jj < 2; ++jj) {
            const float* p = yb + (size_t)(wc * 32 + jj * 16 + l15) * D + k0;
            float v[8];
            *(float4*)&v[0] = *(const float4*)p;
            *(float4*)&v[4] = *(const float4*)(p + 4);
            split8(v, bh[jj], bl[jj]);
        }
        #pragma unroll
        for (int i = 0; i < 2; ++i)
            #pragma unroll
            for (int j = 0; j < 2; ++j) {
                acc[i][j] = __builtin_amdgcn_mfma_f32_16x16x32_bf16(ah[i], bh[j], acc[i][j], 0, 0, 0);
                acc[i][j] = __builtin_amdgcn_mfma_f32_16x16x32_bf16(ah[i], bl[j], acc[i][j], 0, 0, 0);
                acc[i][j] = __builtin_amdgcn_mfma_f32_16x16x32_bf16(al[i], bh[j], acc[i][j], 0, 0, 0);
            }
    }

    // ---- epilogue: cos(mx-my) * exp(-0.5*sqd) ----
    constexpr float INV2PI = 0.15915494309189535f;
    float yv2[2], ymv[2];
    #pragma unroll
    for (int j = 0; j < 2; ++j) {
        const int ml = wc * 32 + j * 16 + l15;
        yv2[j] = sy2[ml]; ymv[j] = smy[ml];
    }
    #pragma unroll
    for (int i = 0; i < 2; ++i) {
        #pragma unroll
        for (int q = 0; q < 4; ++q) {
            const int nl = wr * 32 + i * 16 + lg * 4 + q;   // C/D: row=(lane>>4)*4+reg
            const float x2v = sx2[nl];
            const float mxv = smx[nl];
            float* orow = out + ((size_t)b * N + (n0 + nl)) * (size_t)M + m0;
            #pragma unroll
            for (int j = 0; j < 2; ++j) {
                const int ml = wc * 32 + j * 16 + l15;      // C/D: col=lane&15
                float sqd = fmaxf(x2v + yv2[j] - 2.0f * acc[i][j][q], 0.0f);
                float arg = mxv - ymv[j];
                float r = arg * INV2PI;
                r -= floorf(r);
#if __has_builtin(__builtin_amdgcn_cosf)
                float cosv = __builtin_amdgcn_cosf(r);
#else
                float cosv = __cosf(arg);
#endif
                orow[ml] = cosv * __expf(-0.5f * sqd);
            }
        }
    }
}

extern "C" void kernel_launch(void* const* d_in, const int* in_sizes, int n_in,
                              void* d_out, int out_size, void* d_ws, size_t ws_size,
                              hipStream_t stream)
{
    const float* x   = (const float*)d_in[0];
    const float* y   = (const float*)d_in[1];
    const float* mu  = (const float*)d_in[2];
    const float* ls2 = (const float*)d_in[3];
    float* out = (float*)d_out;

    const int Dd = in_sizes[3];                         // 64
    const long long BN = in_sizes[0] / Dd;              // B*N
    const long long BM = in_sizes[1] / Dd;              // B*M
    const int B = (int)((BN * BM) / (long long)out_size);
    const int N = (int)(BN / B);
    const int M = (int)(BM / B);

    dim3 grid(M / TILE, N / TILE, B);
    dim3 block(256);
    hipLaunchKernelGGL(cosgauss_kernel, grid, block, 0, stream,
                       x, y, mu, ls2, out, N, M);
}

// Round 3
// 73.632 us; speedup vs baseline: 2.6099x; 2.6099x over previous
//
#include <hip/hip_runtime.h>
#include <math.h>

typedef __attribute__((ext_vector_type(8))) short short8;
typedef __attribute__((ext_vector_type(4))) float f32x4;

constexpr int D  = 64;
constexpr int BT = 128;   // main-kernel block tile

__device__ inline float fastcos_rev(float r) {
#if __has_builtin(__builtin_amdgcn_cosf)
    return __builtin_amdgcn_cosf(r);
#else
    return __cosf(r * 6.283185307179586f);
#endif
}
__device__ inline float fastsin_rev(float r) {
#if __has_builtin(__builtin_amdgcn_sinf)
    return __builtin_amdgcn_sinf(r);
#else
    return __sinf(r * 6.283185307179586f);
#endif
}

// split f into bf16 hi + bf16 lo via truncation: f = hi + r exactly, lo = trunc_bf16(r)
__device__ inline void split8(const float* v, short8& hi, short8& lo) {
    #pragma unroll
    for (int j = 0; j < 8; ++j) {
        unsigned u = __builtin_bit_cast(unsigned, v[j]);
        hi[j] = (short)(u >> 16);
        float hf = __builtin_bit_cast(float, u & 0xffff0000u);
        float r  = v[j] - hf;
        lo[j] = (short)(__builtin_bit_cast(unsigned, r) >> 16);
    }
}

// ---------------- prep: scale+split+pack + row stats ----------------
// packed tile layout (per 16 rows): ushort idx = ((kc*4+lg)*16 + row%16)*8 + e
// -> a wave's fragment load (lane = lg*16+l15) is lane*16 bytes: fully coalesced.
__global__ __launch_bounds__(256) void prep_kernel(
    const float* __restrict__ x, const float* __restrict__ y,
    const float* __restrict__ mu, const float* __restrict__ ls2,
    unsigned short* __restrict__ xh, unsigned short* __restrict__ xl,
    unsigned short* __restrict__ yh, unsigned short* __restrict__ yl,
    float4* __restrict__ xst, float4* __restrict__ yst,
    int BN, int BM)
{
    __shared__ float ss[D], sm[D];
    const int t = threadIdx.x;
    if (t < D) { ss[t] = __expf(0.5f * ls2[t]); sm[t] = mu[t]; }
    __syncthreads();

    const int row = blockIdx.x * 256 + t;
    if (row >= BN + BM) return;

    const float* src;
    unsigned short *ph, *pl;
    float4* pst;
    int r;
    if (row < BN) { r = row;      src = x + (size_t)r * D; ph = xh; pl = xl; pst = xst; }
    else          { r = row - BN; src = y + (size_t)r * D; ph = yh; pl = yl; pst = yst; }

    float v[D];
    float h = 0.f, m = 0.f;
    #pragma unroll
    for (int d = 0; d < D; d += 4) {
        float4 u = *(const float4*)(src + d);
        m += u.x * sm[d] + u.y * sm[d+1] + u.z * sm[d+2] + u.w * sm[d+3];
        u.x *= ss[d]; u.y *= ss[d+1]; u.z *= ss[d+2]; u.w *= ss[d+3];
        h += u.x * u.x + u.y * u.y + u.z * u.z + u.w * u.w;
        v[d] = u.x; v[d+1] = u.y; v[d+2] = u.z; v[d+3] = u.w;
    }

    constexpr float INV2PI = 0.15915494309189535f;
    float rr = m * INV2PI;
    rr -= floorf(rr);
    pst[r] = (float4){0.5f * h, fastcos_rev(rr), fastsin_rev(rr), 0.f};

    const size_t tileBase = (size_t)(r >> 4) * 1024;
    const int rl = r & 15;
    #pragma unroll
    for (int sl = 0; sl < 8; ++sl) {
        short8 hi, lo;
        split8(&v[sl * 8], hi, lo);
        *(short8*)(ph + tileBase + (size_t)(sl * 16 + rl) * 8) = hi;
        *(short8*)(pl + tileBase + (size_t)(sl * 16 + rl) * 8) = lo;
    }
}

// ---------------- main: 128x128 tile, 4 waves, wave = 64x64 ----------------
__global__ __launch_bounds__(256) void main_kernel(
    const unsigned short* __restrict__ xh, const unsigned short* __restrict__ xl,
    const unsigned short* __restrict__ yh, const unsigned short* __restrict__ yl,
    const float4* __restrict__ xst, const float4* __restrict__ yst,
    float* __restrict__ out, int N, int M)
{
    __shared__ float4 stA[BT], stB[BT];

    const int b  = blockIdx.z;
    const int n0 = blockIdx.y * BT;
    const int m0 = blockIdx.x * BT;
    const int t  = threadIdx.x;

    if (t < BT) stA[t] = xst[(size_t)b * N + n0 + t];
    else        stB[t - BT] = yst[(size_t)b * M + m0 + (t - BT)];
    __syncthreads();

    const int w = t >> 6, lane = t & 63;
    const int wr = w >> 1, wc = w & 1;
    const int l15 = lane & 15, lg = lane >> 4;

    f32x4 acc[4][4];
    #pragma unroll
    for (int i = 0; i < 4; ++i)
        #pragma unroll
        for (int j = 0; j < 4; ++j)
            acc[i][j] = (f32x4){0.f, 0.f, 0.f, 0.f};

    // tile indices: global row = b*N + n0 + wr*64 + i*16
    const size_t tA0 = ((size_t)(b * N + n0) >> 4) + wr * 4;
    const size_t tB0 = ((size_t)(b * M + m0) >> 4) + wc * 4;
    const int laneOff = lg * 16 + l15;       // *16B within a k-slice

    #pragma unroll
    for (int kc = 0; kc < 2; ++kc) {
        const size_t koff = (size_t)kc * 512 + (size_t)laneOff * 8;   // ushorts
        short8 ah[4], al[4], bh[4], bl[4];
        #pragma unroll
        for (int i = 0; i < 4; ++i) {
            const size_t o = (tA0 + i) * 1024 + koff;
            ah[i] = *(const short8*)(xh + o);
            al[i] = *(const short8*)(xl + o);
        }
        #pragma unroll
        for (int j = 0; j < 4; ++j) {
            const size_t o = (tB0 + j) * 1024 + koff;
            bh[j] = *(const short8*)(yh + o);
            bl[j] = *(const short8*)(yl + o);
        }
        #pragma unroll
        for (int i = 0; i < 4; ++i)
            #pragma unroll
            for (int j = 0; j < 4; ++j) {
                acc[i][j] = __builtin_amdgcn_mfma_f32_16x16x32_bf16(ah[i], bh[j], acc[i][j], 0, 0, 0);
                acc[i][j] = __builtin_amdgcn_mfma_f32_16x16x32_bf16(ah[i], bl[j], acc[i][j], 0, 0, 0);
                acc[i][j] = __builtin_amdgcn_mfma_f32_16x16x32_bf16(al[i], bh[j], acc[i][j], 0, 0, 0);
            }
    }

    // epilogue: out = (cx*cy + sx*sy) * exp(xy - hx - hy)
    float hyv[4], cyv[4], syv[4];
    #pragma unroll
    for (int j = 0; j < 4; ++j) {
        float4 s = stB[wc * 64 + j * 16 + l15];
        hyv[j] = s.x; cyv[j] = s.y; syv[j] = s.z;
    }
    #pragma unroll
    for (int i = 0; i < 4; ++i) {
        #pragma unroll
        for (int q = 0; q < 4; ++q) {
            const int nl = wr * 64 + i * 16 + lg * 4 + q;    // C/D: row=(lane>>4)*4+reg
            const float4 sa = stA[nl];
            float* orow = out + ((size_t)(b * N + n0 + nl)) * (size_t)M + m0 + wc * 64;
            #pragma unroll
            for (int j = 0; j < 4; ++j) {
                const float e  = (acc[i][j][q] - sa.x) - hyv[j];
                const float cv = sa.y * cyv[j] + sa.z * syv[j];
                orow[j * 16 + l15] = cv * __expf(e);         // C/D: col=lane&15
            }
        }
    }
}

// ---------------- fallback (round-1 kernel, used if ws too small) ----------------
constexpr int FTILE = 64;
constexpr int FPAD  = 68;
__global__ __launch_bounds__(256) void fallback_kernel(
    const float* __restrict__ x, const float* __restrict__ y,
    const float* __restrict__ mu, const float* __restrict__ ls2,
    float* __restrict__ out, int N, int M)
{
    __shared__ float xs[FTILE][FPAD];
    __shared__ float ys[FTILE][FPAD];
    __shared__ float musc[D];
    __shared__ float sx2[FTILE], smx[FTILE], sy2[FTILE], smy[FTILE];

    const int b  = blockIdx.z;
    const int n0 = blockIdx.y * FTILE;
    const int m0 = blockIdx.x * FTILE;
    const int t  = threadIdx.x;
    const int cc = t & 15, rr = t >> 4, c4 = cc * 4;

    const float s0 = __expf(0.5f * ls2[c4+0]);
    const float s1 = __expf(0.5f * ls2[c4+1]);
    const float s2 = __expf(0.5f * ls2[c4+2]);
    const float s3 = __expf(0.5f * ls2[c4+3]);
    const float* xb = x + ((size_t)b * N + n0) * D;
    const float* yb = y + ((size_t)b * M + m0) * D;

    #pragma unroll
    for (int r = 0; r < 4; ++r) {
        const int row = rr * 4 + r;
        const float4 vx = *(const float4*)(xb + row * D + c4);
        const float4 vy = *(const float4*)(yb + row * D + c4);
        xs[row][c4+0] = vx.x * s0; xs[row][c4+1] = vx.y * s1;
        xs[row][c4+2] = vx.z * s2; xs[row][c4+3] = vx.w * s3;
        ys[row][c4+0] = vy.x * s0; ys[row][c4+1] = vy.y * s1;
        ys[row][c4+2] = vy.z * s2; ys[row][c4+3] = vy.w * s3;
    }
    if (t < D) musc[t] = mu[t] * __expf(-0.5f * ls2[t]);
    __syncthreads();

    if (t < 64) {
        float a2 = 0.f, am = 0.f;
        #pragma unroll
        for (int d4 = 0; d4 < D; d4 += 4) {
            const float4 v = *(const float4*)&xs[t][d4];
            const float4 m4 = *(const float4*)&musc[d4];
            a2 += v.x*v.x + v.y*v.y + v.z*v.z + v.w*v.w;
            am += v.x*m4.x + v.y*m4.y + v.z*m4.z + v.w*m4.w;
        }
        sx2[t] = a2; smx[t] = am;
    } else if (t < 128) {
        const int r2 = t - 64;
        float a2 = 0.f, am = 0.f;
        #pragma unroll
        for (int d4 = 0; d4 < D; d4 += 4) {
            const float4 v = *(const float4*)&ys[r2][d4];
            const float4 m4 = *(const float4*)&musc[d4];
            a2 += v.x*v.x + v.y*v.y + v.z*v.z + v.w*v.w;
            am += v.x*m4.x + v.y*m4.y + v.z*m4.z + v.w*m4.w;
        }
        sy2[r2] = a2; smy[r2] = am;
    }
    __syncthreads();

    const int tx = t & 15, ty = t >> 4;
    float acc[4][4] = {};
    #pragma unroll
    for (int d = 0; d < D; d += 4) {
        float4 a4[4], b4[4];
        #pragma unroll
        for (int i = 0; i < 4; ++i) a4[i] = *(const float4*)&xs[ty + 16*i][d];
        #pragma unroll
        for (int j = 0; j < 4; ++j) b4[j] = *(const float4*)&ys[tx + 16*j][d];
        #pragma unroll
        for (int i = 0; i < 4; ++i)
            #pragma unroll
            for (int j = 0; j < 4; ++j) {
                acc[i][j] += a4[i].x*b4[j].x + a4[i].y*b4[j].y
                           + a4[i].z*b4[j].z + a4[i].w*b4[j].w;
            }
    }

    constexpr float INV2PI = 0.15915494309189535f;
    #pragma unroll
    for (int i = 0; i < 4; ++i) {
        const int nl = ty + 16*i;
        float* orow = out + ((size_t)(b * N + n0 + nl)) * (size_t)M + m0;
        const float x2v = sx2[nl], mxv = smx[nl];
        #pragma unroll
        for (int j = 0; j < 4; ++j) {
            const int ml = tx + 16*j;
            float sqd = fmaxf(x2v + sy2[ml] - 2.0f*acc[i][j], 0.0f);
            float r = (mxv - smy[ml]) * INV2PI;
            r -= floorf(r);
            orow[ml] = fastcos_rev(r) * __expf(-0.5f * sqd);
        }
    }
}

extern "C" void kernel_launch(void* const* d_in, const int* in_sizes, int n_in,
                              void* d_out, int out_size, void* d_ws, size_t ws_size,
                              hipStream_t stream)
{
    const float* x   = (const float*)d_in[0];
    const float* y   = (const float*)d_in[1];
    const float* mu  = (const float*)d_in[2];
    const float* ls2 = (const float*)d_in[3];
    float* out = (float*)d_out;

    const int Dd = in_sizes[3];
    const long long BN = in_sizes[0] / Dd;   // B*N
    const long long BM = in_sizes[1] / Dd;   // B*M
    const int B = (int)((BN * BM) / (long long)out_size);
    const int N = (int)(BN / B);
    const int M = (int)(BM / B);

    const size_t need = (size_t)(BN + BM) * D * 2 * 2   // hi+lo bf16
                      + (size_t)(BN + BM) * sizeof(float4);

    if (ws_size >= need && (N % BT) == 0 && (M % BT) == 0) {
        unsigned short* xh = (unsigned short*)d_ws;
        unsigned short* xl = xh + (size_t)BN * D;
        unsigned short* yh = xl + (size_t)BN * D;
        unsigned short* yl = yh + (size_t)BM * D;
        float4* xst = (float4*)(yl + (size_t)BM * D);
        float4* yst = xst + BN;

        const int rows = (int)(BN + BM);
        hipLaunchKernelGGL(prep_kernel, dim3((rows + 255) / 256), dim3(256), 0, stream,
                           x, y, mu, ls2, xh, xl, yh, yl, xst, yst, (int)BN, (int)BM);
        hipLaunchKernelGGL(main_kernel, dim3(M / BT, N / BT, B), dim3(256), 0, stream,
                           xh, xl, yh, yl, xst, yst, out, N, M);
    } else {
        hipLaunchKernelGGL(fallback_kernel, dim3(M / FTILE, N / FTILE, B), dim3(256), 0, stream,
                           x, y, mu, ls2, out, N, M);
    }
}